// Round 1
// 7662.733 us; speedup vs baseline: 1.1998x; 1.1998x over previous
//
#include <hip/hip_runtime.h>
#include <hip/hip_bf16.h>
#include <math.h>

#define S_ 64
#define B_ 64
#define H_ 512
#define E_ 512
#define L_ 2
#define V_ 32000

#define SB_   (S_*B_)        // 4096
#define SBE_  (S_*B_*E_)     // 2097152
#define SBH_  (S_*B_*H_)     // 2097152
#define BH_   (B_*H_)        // 32768
#define KP_   1536           // split-fp16 extended K (3 * 512)

typedef _Float16 f16x8 __attribute__((ext_vector_type(8)));
typedef _Float16 f16x4 __attribute__((ext_vector_type(4)));
typedef float    f32x4 __attribute__((ext_vector_type(4)));

// ---------------------------------------------------------------------------
// Embedding gather: x[s,b,:] = emb[tokens[s,b],:]   (float4 vectorized)
// ---------------------------------------------------------------------------
__global__ __launch_bounds__(256) void embed_k(const int* __restrict__ tok,
                                               const float* __restrict__ emb,
                                               float* __restrict__ x) {
    int idx = blockIdx.x * 256 + threadIdx.x;   // over S*B*(E/4)
    int e4 = idx & (E_/4 - 1);                  // 128 float4 per row
    int sb = idx >> 7;
    int tk = tok[sb];
    *(float4*)(x + (size_t)sb * E_ + e4 * 4) =
        *(const float4*)(emb + (size_t)tk * E_ + e4 * 4);
}

// ---------------------------------------------------------------------------
// Generic fp32 GEMM + bias (still used for the 6 small precompute GEMMs)
// ---------------------------------------------------------------------------
__global__ __launch_bounds__(256) void gemm_bias(
    const float* __restrict__ A, int lda,
    const float* __restrict__ W, int ldw,
    const float* __restrict__ bias,
    float* __restrict__ C, int ldc,
    int K) {
    __shared__ float As[16][68];   // transposed: As[k][m]
    __shared__ float Bs[16][68];   // Bs[k][n]

    const int tid = threadIdx.x;
    const int tx = tid & 15;       // n-tile lane
    const int ty = tid >> 4;       // m-tile lane
    const int n0 = blockIdx.x * 64;
    const int m0 = blockIdx.y * 64;

    float acc[4][4] = {};

    for (int k0 = 0; k0 < K; k0 += 16) {
        {
            int i  = tid >> 2;
            int j4 = tid & 3;
            const float4 av = *(const float4*)(A + (size_t)(m0 + i) * lda + k0 + j4 * 4);
            As[j4 * 4 + 0][i] = av.x;
            As[j4 * 4 + 1][i] = av.y;
            As[j4 * 4 + 2][i] = av.z;
            As[j4 * 4 + 3][i] = av.w;
        }
        {
            int r  = tid >> 4;
            int c4 = tid & 15;
            *(float4*)(&Bs[r][c4 * 4]) =
                *(const float4*)(W + (size_t)(k0 + r) * ldw + n0 + c4 * 4);
        }
        __syncthreads();
        #pragma unroll
        for (int kk = 0; kk < 16; kk++) {
            float4 a4 = *(float4*)(&As[kk][ty * 4]);
            float4 b4 = *(float4*)(&Bs[kk][tx * 4]);
            acc[0][0] += a4.x * b4.x; acc[0][1] += a4.x * b4.y; acc[0][2] += a4.x * b4.z; acc[0][3] += a4.x * b4.w;
            acc[1][0] += a4.y * b4.x; acc[1][1] += a4.y * b4.y; acc[1][2] += a4.y * b4.z; acc[1][3] += a4.y * b4.w;
            acc[2][0] += a4.z * b4.x; acc[2][1] += a4.z * b4.y; acc[2][2] += a4.z * b4.z; acc[2][3] += a4.z * b4.w;
            acc[3][0] += a4.w * b4.x; acc[3][1] += a4.w * b4.y; acc[3][2] += a4.w * b4.z; acc[3][3] += a4.w * b4.w;
        }
        __syncthreads();
    }

    float4 bv = *(const float4*)(bias + n0 + tx * 4);
    #pragma unroll
    for (int i = 0; i < 4; i++) {
        int row = m0 + ty * 4 + i;
        float4 out;
        out.x = acc[i][0] + bv.x;
        out.y = acc[i][1] + bv.y;
        out.z = acc[i][2] + bv.z;
        out.w = acc[i][3] + bv.w;
        *(float4*)(C + (size_t)row * ldc + n0 + tx * 4) = out;
    }
}

// ---------------------------------------------------------------------------
// r/z gate step (unchanged)
// ---------------------------------------------------------------------------
__device__ __forceinline__ float sigmoidf_(float xv) {
    float e = __expf(-fabsf(xv));
    float s = 1.f / (1.f + e);
    return xv >= 0.f ? s : 1.f - s;
}

__global__ __launch_bounds__(256) void rz_step(
    const float* __restrict__ Pr_t, const float* __restrict__ Pz_t,
    const float* __restrict__ Wr_hid, const float* __restrict__ Wz_hid,
    const float* __restrict__ h_prev,
    float* __restrict__ zbuf, float* __restrict__ rhbuf) {
    __shared__ float hs[64][132];
    const int bid = blockIdx.x;
    const int g = bid >> 5;
    const int ct = bid & 31;
    const int tid = threadIdx.x;
    const int c = ct * 16 + (tid & 15);
    const int bg = tid >> 4;

    const float* Wg = g ? Wz_hid : Wr_hid;
    const float* P  = g ? Pz_t   : Pr_t;

    float acc[4] = {0.f, 0.f, 0.f, 0.f};

    for (int kk = 0; kk < H_; kk += 128) {
        #pragma unroll
        for (int q = 0; q < 8; q++) {
            int idx = q * 256 + tid;
            int row = idx >> 5;
            int c4  = idx & 31;
            *(float4*)(&hs[row][c4 * 4]) =
                *(const float4*)(h_prev + row * H_ + kk + c4 * 4);
        }
        __syncthreads();
        const float* Wp = Wg + (size_t)kk * H_ + c;
        #pragma unroll 4
        for (int k = 0; k < 128; k++) {
            float w = Wp[(size_t)k * H_];
            #pragma unroll
            for (int i = 0; i < 4; i++)
                acc[i] += w * hs[bg * 4 + i][k];
        }
        __syncthreads();
    }

    #pragma unroll
    for (int i = 0; i < 4; i++) {
        int b = bg * 4 + i;
        float pre = P[b * H_ + c] + acc[i];
        float v = sigmoidf_(pre);
        if (g == 0) rhbuf[b * H_ + c] = v * h_prev[b * H_ + c];
        else        zbuf[b * H_ + c]  = v;
    }
}

// ---------------------------------------------------------------------------
// candidate + update step (unchanged)
// ---------------------------------------------------------------------------
__global__ __launch_bounds__(256) void hh_step(
    const float* __restrict__ Ph_t,
    const float* __restrict__ Wh_hid,
    const float* __restrict__ rh,
    const float* __restrict__ h_prev,
    const float* __restrict__ zbuf,
    float* __restrict__ h_out) {
    __shared__ float hs[64][132];
    const int ct = blockIdx.x;
    const int tid = threadIdx.x;
    const int c = ct * 16 + (tid & 15);
    const int bg = tid >> 4;

    float acc[4] = {0.f, 0.f, 0.f, 0.f};

    for (int kk = 0; kk < H_; kk += 128) {
        #pragma unroll
        for (int q = 0; q < 8; q++) {
            int idx = q * 256 + tid;
            int row = idx >> 5;
            int c4  = idx & 31;
            *(float4*)(&hs[row][c4 * 4]) =
                *(const float4*)(rh + row * H_ + kk + c4 * 4);
        }
        __syncthreads();
        const float* Wp = Wh_hid + (size_t)kk * H_ + c;
        #pragma unroll 4
        for (int k = 0; k < 128; k++) {
            float w = Wp[(size_t)k * H_];
            #pragma unroll
            for (int i = 0; i < 4; i++)
                acc[i] += w * hs[bg * 4 + i][k];
        }
        __syncthreads();
    }

    #pragma unroll
    for (int i = 0; i < 4; i++) {
        int b = bg * 4 + i;
        float pre = Ph_t[b * H_ + c] + acc[i];
        float hhv = tanhf(pre);
        float z = zbuf[b * H_ + c];
        float h = h_prev[b * H_ + c];
        h_out[b * H_ + c] = (1.f - z) * h + z * hhv;
    }
}

// ---------------------------------------------------------------------------
// Split-fp16 cast of the final hidden sequence:
//   A'[m, k]      = fp16(x)              (ah)
//   A'[m, 512+k]  = fp16((x-ah) * 32)    (al * 2^5)
//   A'[m, 1024+k] = fp16(ah / 16)        (ah * 2^-4)
// Scales keep everything fp16-normal; pairs with castB's segments so that
// sum over K'=1536 of A'*B' = ah*bh + al*bh + ah*bl  (~22-bit mantissa).
// grid = SBE_/4/256 = 2048 blocks.
// ---------------------------------------------------------------------------
__global__ __launch_bounds__(256) void castA_k(const float* __restrict__ in,
                                               _Float16* __restrict__ A2) {
    int idx = blockIdx.x * 256 + threadIdx.x;   // over 4096 * 128
    int m = idx >> 7;
    int q = idx & 127;
    float4 xv = *(const float4*)(in + (size_t)m * H_ + q * 4);
    float xs[4] = {xv.x, xv.y, xv.z, xv.w};
    f16x4 hi, lo, sc;
    #pragma unroll
    for (int i = 0; i < 4; i++) {
        _Float16 ah = (_Float16)xs[i];
        float ahf = (float)ah;
        hi[i] = ah;
        lo[i] = (_Float16)((xs[i] - ahf) * 32.0f);
        sc[i] = (_Float16)(ahf * 0.0625f);
    }
    _Float16* row = A2 + (size_t)m * KP_ + q * 4;
    *(f16x4*)(row)        = hi;
    *(f16x4*)(row + 512)  = lo;
    *(f16x4*)(row + 1024) = sc;
}

// ---------------------------------------------------------------------------
// Split-fp16 cast + transpose of Wout [512, 32000] -> Bt [32000, 1536]:
//   Bt[v, h]      = fp16(w)              (bh)   — pairs with ah
//   Bt[v, 512+h]  = fp16(bh / 32)        (bh * 2^-5) — pairs with al*2^5
//   Bt[v, 1024+h] = fp16((w-bh) * 16)    (bl * 2^4)  — pairs with ah*2^-4
// grid = dim3(V_/64, H_/64) = (500, 8), 256 threads.
// ---------------------------------------------------------------------------
__global__ __launch_bounds__(256) void castB_k(const float* __restrict__ W,
                                               _Float16* __restrict__ Bt) {
    __shared__ float ws[64][68];
    const int v0 = blockIdx.x * 64;
    const int h0 = blockIdx.y * 64;
    const int tid = threadIdx.x;

    #pragma unroll
    for (int q = 0; q < 4; q++) {
        int idx = q * 256 + tid;        // over 64 h-rows x 16 float4
        int h  = idx >> 4;
        int v4 = idx & 15;
        *(float4*)(&ws[h][v4 * 4]) =
            *(const float4*)(W + (size_t)(h0 + h) * V_ + v0 + v4 * 4);
    }
    __syncthreads();

    const int v  = tid >> 2;   // 0..63
    const int hq = tid & 3;    // 0..3
    #pragma unroll
    for (int j = 0; j < 2; j++) {
        int hb = j * 32 + hq * 8;       // lanes 0..3 write contiguous 64B
        f16x8 hi, lo, sc;
        #pragma unroll
        for (int i = 0; i < 8; i++) {
            float wv = ws[hb + i][v];
            _Float16 bh = (_Float16)wv;
            float bhf = (float)bh;
            hi[i] = bh;
            sc[i] = (_Float16)(bhf * 0.03125f);
            lo[i] = (_Float16)((wv - bhf) * 16.0f);
        }
        _Float16* row = Bt + (size_t)(v0 + v) * KP_ + h0 + hb;
        *(f16x8*)(row)        = hi;
        *(f16x8*)(row + 512)  = sc;
        *(f16x8*)(row + 1024) = lo;
    }
}

// ---------------------------------------------------------------------------
// MFMA logits GEMM: C[4096, 32000] = A'[4096,1536] @ Bt[32000,1536]^T + bout
// 128x128 tile, 4 waves (2x2 of 64x64), 16x16x32 f16 MFMA, BK=64.
// global_load_lds 16B staging, XOR-swizzled LDS (slot ^= row&7) for
// conflict-free ds_read_b128 fragment loads (guide T2 / G4).
// grid = dim3(V_/128, SB_/128) = (250, 32).
// ---------------------------------------------------------------------------
__global__ __launch_bounds__(256) void gemm_logits(
    const _Float16* __restrict__ Ag,   // [4096, KP_]
    const _Float16* __restrict__ Bg,   // [32000, KP_]
    const float* __restrict__ bias,    // [32000]
    float* __restrict__ C) {           // [4096, 32000]
    __shared__ __align__(16) _Float16 As[128 * 64];
    __shared__ __align__(16) _Float16 Bs[128 * 64];

    const int tid  = threadIdx.x;
    const int lane = tid & 63;
    const int w    = tid >> 6;
    const int n0   = blockIdx.x * 128;
    const int m0   = blockIdx.y * 128;
    const int wm   = (w >> 1) * 64;
    const int wn   = (w & 1) * 64;

    f32x4 acc[4][4];
    #pragma unroll
    for (int i = 0; i < 4; i++)
        #pragma unroll
        for (int j = 0; j < 4; j++)
            acc[i][j] = (f32x4){0.f, 0.f, 0.f, 0.f};

    const int grow  = lane >> 3;            // row within 8-row chunk
    const int gslot = (lane & 7) ^ grow;    // pre-swizzled global 16B slot

    for (int kt = 0; kt < KP_ / 64; ++kt) {
        const int k0 = kt * 64;
        // ---- stage A-tile [128][64] and B-tile [128][64] (16 chunks each) --
        #pragma unroll
        for (int q = 0; q < 4; ++q) {
            int ch  = w * 4 + q;            // 1KB chunk = 8 rows of 128B
            int row = ch * 8 + grow;
            const _Float16* ga = Ag + (size_t)(m0 + row) * KP_ + k0 + gslot * 8;
            const _Float16* gb = Bg + (size_t)(n0 + row) * KP_ + k0 + gslot * 8;
            __builtin_amdgcn_global_load_lds(
                (const __attribute__((address_space(1))) void*)ga,
                (__attribute__((address_space(3))) void*)(As + ch * 512), 16, 0, 0);
            __builtin_amdgcn_global_load_lds(
                (const __attribute__((address_space(1))) void*)gb,
                (__attribute__((address_space(3))) void*)(Bs + ch * 512), 16, 0, 0);
        }
        __syncthreads();   // compiler drains vmcnt(0) before s_barrier

        // ---- compute: 2 K-slices of 32, 16 MFMA each ----------------------
        #pragma unroll
        for (int ks = 0; ks < 2; ++ks) {
            f16x8 af[4], bf[4];
            #pragma unroll
            for (int i = 0; i < 4; ++i) {
                int arow  = wm + i * 16 + (lane & 15);
                int aslot = (ks * 4 + (lane >> 4)) ^ (arow & 7);
                af[i] = *(const f16x8*)(As + arow * 64 + aslot * 8);
                int brow  = wn + i * 16 + (lane & 15);
                int bslot = (ks * 4 + (lane >> 4)) ^ (brow & 7);
                bf[i] = *(const f16x8*)(Bs + brow * 64 + bslot * 8);
            }
            #pragma unroll
            for (int mi = 0; mi < 4; ++mi)
                #pragma unroll
                for (int nj = 0; nj < 4; ++nj)
                    acc[mi][nj] = __builtin_amdgcn_mfma_f32_16x16x32_f16(
                        af[mi], bf[nj], acc[mi][nj], 0, 0, 0);
        }
        __syncthreads();
    }

    // ---- epilogue: C/D layout col=lane&15, row=(lane>>4)*4+j (m89) --------
    #pragma unroll
    for (int nj = 0; nj < 4; ++nj) {
        int col = n0 + wn + nj * 16 + (lane & 15);
        float bv = bias[col];
        #pragma unroll
        for (int mi = 0; mi < 4; ++mi) {
            int rb = m0 + wm + mi * 16 + (lane >> 4) * 4;
            #pragma unroll
            for (int j = 0; j < 4; ++j)
                C[(size_t)(rb + j) * V_ + col] = acc[mi][nj][j] + bv;
        }
    }
}

// ---------------------------------------------------------------------------
extern "C" void kernel_launch(void* const* d_in, const int* in_sizes, int n_in,
                              void* d_out, int out_size, void* d_ws, size_t ws_size,
                              hipStream_t stream) {
    const int*   tokens = (const int*)  d_in[0];
    const float* hidden = (const float*)d_in[1];   // [L,B,H] zeros
    const float* emb    = (const float*)d_in[2];   // [V,E]
    const float* Wr     = (const float*)d_in[3];   // [L,E+H,H]
    const float* br     = (const float*)d_in[4];   // [L,H]
    const float* Wz     = (const float*)d_in[5];
    const float* bz     = (const float*)d_in[6];
    const float* Wh     = (const float*)d_in[7];
    const float* bh     = (const float*)d_in[8];
    const float* Wout   = (const float*)d_in[9];   // [H,V]
    const float* bout   = (const float*)d_in[10];  // [V]

    float* out = (float*)d_out;            // logits [S,B,V] then hidden [L,B,H]
    float* out_hidden = out + (size_t)SB_ * V_;

    // workspace layout (fp32 region then fp16 region)
    float* ws = (float*)d_ws;
    float* x     = ws;                 // SBE_
    float* hseq1 = x + SBE_;           // SBH_
    float* hseq2 = hseq1 + SBH_;       // SBH_
    float* Pr    = hseq2 + SBH_;       // SBH_
    float* Pz    = Pr + SBH_;          // SBH_
    float* Ph    = Pz + SBH_;          // SBH_
    float* zbuf  = Ph + SBH_;          // BH_
    float* rhbuf = zbuf + BH_;         // BH_
    _Float16* A2 = (_Float16*)(rhbuf + BH_);        // SB_ * KP_   (12.6 MB)
    _Float16* Bt = A2 + (size_t)SB_ * KP_;          // V_ * KP_    (98.3 MB)

    // 1. embedding
    embed_k<<<SBE_ / 4 / 256, 256, 0, stream>>>(tokens, emb, x);

    // 2. split-fp16 cast + transpose of Wout (independent of recurrence)
    castB_k<<<dim3(V_ / 64, H_ / 64), 256, 0, stream>>>(Wout, Bt);

    const int WL = (E_ + H_) * H_;     // per-layer weight matrix size
    const float* layer_in[2] = {x, hseq1};
    float* hseqs[2] = {hseq1, hseq2};

    for (int l = 0; l < L_; l++) {
        const float* A = layer_in[l];
        const float* Wr_l = Wr + (size_t)l * WL;
        const float* Wz_l = Wz + (size_t)l * WL;
        const float* Wh_l = Wh + (size_t)l * WL;

        // input-side contributions for all timesteps
        dim3 gpre(H_ / 64, SB_ / 64);
        gemm_bias<<<gpre, 256, 0, stream>>>(A, E_, Wr_l, H_, br + l * H_, Pr, H_, E_);
        gemm_bias<<<gpre, 256, 0, stream>>>(A, E_, Wz_l, H_, bz + l * H_, Pz, H_, E_);
        gemm_bias<<<gpre, 256, 0, stream>>>(A, E_, Wh_l, H_, bh + l * H_, Ph, H_, E_);

        const float* Wr_hid = Wr_l + (size_t)E_ * H_;
        const float* Wz_hid = Wz_l + (size_t)E_ * H_;
        const float* Wh_hid = Wh_l + (size_t)E_ * H_;

        for (int t = 0; t < S_; t++) {
            const float* h_prev = (t == 0) ? (hidden + (size_t)l * BH_)
                                           : (hseqs[l] + (size_t)(t - 1) * BH_);
            rz_step<<<64, 256, 0, stream>>>(Pr + (size_t)t * BH_, Pz + (size_t)t * BH_,
                                            Wr_hid, Wz_hid, h_prev, zbuf, rhbuf);
            hh_step<<<32, 256, 0, stream>>>(Ph + (size_t)t * BH_, Wh_hid, rhbuf,
                                            h_prev, zbuf, hseqs[l] + (size_t)t * BH_);
        }

        hipMemcpyAsync(out_hidden + (size_t)l * BH_, hseqs[l] + (size_t)(S_ - 1) * BH_,
                       (size_t)BH_ * sizeof(float), hipMemcpyDeviceToDevice, stream);
    }

    // 3. split-fp16 cast of final hidden sequence
    castA_k<<<SBE_ / 4 / 256, 256, 0, stream>>>(hseq2, A2);

    // 4. logits = A2 @ Bt^T + bout via f16 MFMA (emulated fp32 precision)
    gemm_logits<<<dim3(V_ / 128, SB_ / 128), 256, 0, stream>>>(A2, Bt, bout, out);
}